// Round 15
// baseline (278.162 us; speedup 1.0000x reference)
//
#include <hip/hip_runtime.h>
#include <math.h>

#define BATCH 4
#define SEQ 4096
#define DMODEL 1024
#define HD 64
#define EE 192          // 3*HD
#define KSP 409         // max(1, int(4096*0.1))
#define SCALE 0.125f
#define LISTCAP 512
#define INV2048 (1.0f/2048.0f)

using half8 = __attribute__((ext_vector_type(8))) _Float16;
using half4 = __attribute__((ext_vector_type(4))) _Float16;
using f32x4 = __attribute__((ext_vector_type(4))) float;

__device__ __forceinline__ unsigned int fkey(float f) {
    unsigned int u = __float_as_uint(f);
    return (u & 0x80000000u) ? ~u : (u | 0x80000000u);
}
__device__ __forceinline__ float ikey(unsigned int k) {
    unsigned int u = (k & 0x80000000u) ? (k ^ 0x80000000u) : ~k;
    return __uint_as_float(u);
}

// ---------------- K0: split W into fp16 hi/lo (lo scaled by 2^11) ----------------
__global__ __launch_bounds__(256) void wsplit_kernel(const float* __restrict__ W,
                                                     _Float16* __restrict__ Whi,
                                                     _Float16* __restrict__ Wlo) {
    int i = blockIdx.x * 1024 + threadIdx.x * 4;
    float4 w = *(const float4*)&W[i];
    float f[4] = {w.x, w.y, w.z, w.w};
    half4 hv, lv;
    #pragma unroll
    for (int j = 0; j < 4; ++j) {
        _Float16 h = (_Float16)f[j];
        hv[j] = h;
        lv[j] = (_Float16)((f[j] - (float)h) * 2048.0f);
    }
    *(half4*)&Whi[i] = hv;
    *(half4*)&Wlo[i] = lv;
}

// ---------------- K1: QKV via fp16 split-3 MFMA, double-buffered LDS (1 barrier/iter) ----------------
#define AH_OFF 0
#define AL_OFF 4096
#define BH_OFF 8192
#define BL_OFF 14336
#define BUFSZ 20480

__global__ __launch_bounds__(256) void qkv_mfma_kernel(const float* __restrict__ X,
        const _Float16* __restrict__ Whi, const _Float16* __restrict__ Wlo,
        _Float16* __restrict__ QH, _Float16* __restrict__ QL,
        _Float16* __restrict__ KH, _Float16* __restrict__ KL,
        float* __restrict__ V) {
    __shared__ __align__(16) unsigned char lds[2 * BUFSZ];
    const int t = threadIdx.x;
    const int lane = t & 63;
    const int wv = t >> 6;
    const int wr = wv >> 1, wc = wv & 1;
    const int L = blockIdx.x;
    const int pair = ((L >> 4) << 3) + (L & 7);
    const int ny = (L >> 3) & 1;
    const int m0 = pair * 64;
    const int n0 = ny * 96;

    const int ar = t >> 2;
    const int akc = (t & 3) * 8;
    const int aw_addr = ((ar * 64 + (t & 3) * 16) ^ ((ar & 7) << 4));
    const int br0 = t >> 2;
    const int bw0 = ((br0 * 64 + (t & 3) * 16) ^ ((br0 & 7) << 4));
    const int br1 = 64 + (t >> 2);
    const int bw1 = ((br1 * 64 + (t & 3) * 16) ^ ((br1 & 7) << 4));

    float4 xa, xb;
    uint4 pbh0, pbl0, pbh1, pbl1;

    #define LOADG(K0) { \
        const float* xp = X + (size_t)(m0 + ar) * DMODEL + (K0) + akc; \
        xa = *(const float4*)xp; xb = *(const float4*)(xp + 4); \
        size_t wo0 = (size_t)(n0 + br0) * DMODEL + (K0) + akc; \
        pbh0 = *(const uint4*)(Whi + wo0); pbl0 = *(const uint4*)(Wlo + wo0); \
        if (t < 128) { \
            size_t wo1 = (size_t)(n0 + br1) * DMODEL + (K0) + akc; \
            pbh1 = *(const uint4*)(Whi + wo1); pbl1 = *(const uint4*)(Wlo + wo1); \
        } }

    #define WRITE_LDS(B) { \
        float f[8] = {xa.x, xa.y, xa.z, xa.w, xb.x, xb.y, xb.z, xb.w}; \
        half8 hv, lv; \
        _Pragma("unroll") \
        for (int i2 = 0; i2 < 8; ++i2) { \
            _Float16 h = (_Float16)f[i2]; \
            hv[i2] = h; \
            lv[i2] = (_Float16)((f[i2] - (float)h) * 2048.0f); \
        } \
        *(half8*)(lds + (B) + AH_OFF + aw_addr) = hv; \
        *(half8*)(lds + (B) + AL_OFF + aw_addr) = lv; \
        *(uint4*)(lds + (B) + BH_OFF + bw0) = pbh0; \
        *(uint4*)(lds + (B) + BL_OFF + bw0) = pbl0; \
        if (t < 128) { \
            *(uint4*)(lds + (B) + BH_OFF + bw1) = pbh1; \
            *(uint4*)(lds + (B) + BL_OFF + bw1) = pbl1; \
        } }

    f32x4 hh[2][3], xx[2][3];
    #pragma unroll
    for (int mi = 0; mi < 2; ++mi)
        #pragma unroll
        for (int ni = 0; ni < 3; ++ni) {
            hh[mi][ni] = (f32x4){0.f, 0.f, 0.f, 0.f};
            xx[mi][ni] = (f32x4){0.f, 0.f, 0.f, 0.f};
        }

    LOADG(0);
    WRITE_LDS(0);
    __syncthreads();

    const int kb = (lane >> 4) << 4;

    for (int it = 0; it < 32; ++it) {
        const int cur = (it & 1) * BUFSZ;
        if (it < 31) LOADG((it + 1) * 32);

        half8 ah[2], al[2], bh[3], bl[3];
        #pragma unroll
        for (int mi = 0; mi < 2; ++mi) {
            int ra = wr * 32 + mi * 16 + (lane & 15);
            int ad = cur + ((ra * 64 + kb) ^ ((ra & 7) << 4));
            ah[mi] = *(const half8*)(lds + AH_OFF + ad);
            al[mi] = *(const half8*)(lds + AL_OFF + ad);
        }
        #pragma unroll
        for (int ni = 0; ni < 3; ++ni) {
            int rb = wc * 48 + ni * 16 + (lane & 15);
            int bd = cur + ((rb * 64 + kb) ^ ((rb & 7) << 4));
            bh[ni] = *(const half8*)(lds + BH_OFF + bd);
            bl[ni] = *(const half8*)(lds + BL_OFF + bd);
        }
        #pragma unroll
        for (int mi = 0; mi < 2; ++mi)
            #pragma unroll
            for (int ni = 0; ni < 3; ++ni) {
                hh[mi][ni] = __builtin_amdgcn_mfma_f32_16x16x32_f16(ah[mi], bh[ni], hh[mi][ni], 0, 0, 0);
                xx[mi][ni] = __builtin_amdgcn_mfma_f32_16x16x32_f16(ah[mi], bl[ni], xx[mi][ni], 0, 0, 0);
                xx[mi][ni] = __builtin_amdgcn_mfma_f32_16x16x32_f16(al[mi], bh[ni], xx[mi][ni], 0, 0, 0);
            }
        if (it < 31) {
            WRITE_LDS(BUFSZ - cur);   // write next tile into the buffer not being read
            __syncthreads();
        }
    }

    #pragma unroll
    for (int mi = 0; mi < 2; ++mi)
        #pragma unroll
        for (int ni = 0; ni < 3; ++ni) {
            int col = n0 + wc * 48 + ni * 16 + (lane & 15);
            int rowb = m0 + wr * 32 + mi * 16 + ((lane >> 4) << 2);
            #pragma unroll
            for (int j = 0; j < 4; ++j) {
                float val = hh[mi][ni][j] + xx[mi][ni][j] * INV2048;
                int row = rowb + j;
                if (col < 64) {
                    _Float16 h = (_Float16)val;
                    QH[(size_t)row * HD + col] = h;
                    QL[(size_t)row * HD + col] = (_Float16)((val - (float)h) * 2048.0f);
                } else if (col < 128) {
                    _Float16 h = (_Float16)val;
                    KH[(size_t)row * HD + (col - 64)] = h;
                    KL[(size_t)row * HD + (col - 64)] = (_Float16)((val - (float)h) * 2048.0f);
                } else {
                    V[(size_t)row * HD + (col - 128)] = val;
                }
            }
        }
}

// ---------------- K2: scores via fp16 split-3 MFMA ----------------
#define SQH_OFF 0
#define SQL_OFF 16384
#define SKH_OFF 32768
#define SKL_OFF 40960

__global__ __launch_bounds__(256) void scores_mfma_kernel(
        const _Float16* __restrict__ QH, const _Float16* __restrict__ QL,
        const _Float16* __restrict__ KH, const _Float16* __restrict__ KL,
        float* __restrict__ Sc) {
    __shared__ __align__(16) unsigned char lds[49152];
    const int t = threadIdx.x;
    const int lane = t & 63;
    const int wv = t >> 6;
    const int i0 = blockIdx.y * 128;
    const int j0 = blockIdx.x * 64;

    #pragma unroll
    for (int u = 0; u < 4; ++u) {
        int ch = t + 256 * u;
        int r = ch >> 3;
        int kbyte = (ch & 7) * 16;
        int ad = (r * 128 + kbyte) ^ ((r & 7) << 4);
        *(uint4*)(lds + SQH_OFF + ad) = *(const uint4*)((const char*)QH + (size_t)(i0 + r) * 128 + kbyte);
        *(uint4*)(lds + SQL_OFF + ad) = *(const uint4*)((const char*)QL + (size_t)(i0 + r) * 128 + kbyte);
    }
    #pragma unroll
    for (int u = 0; u < 2; ++u) {
        int ch = t + 256 * u;
        int r = ch >> 3;
        int kbyte = (ch & 7) * 16;
        int ad = (r * 128 + kbyte) ^ ((r & 7) << 4);
        *(uint4*)(lds + SKH_OFF + ad) = *(const uint4*)((const char*)KH + (size_t)(j0 + r) * 128 + kbyte);
        *(uint4*)(lds + SKL_OFF + ad) = *(const uint4*)((const char*)KL + (size_t)(j0 + r) * 128 + kbyte);
    }
    __syncthreads();

    f32x4 hh[2][4], xx[2][4];
    #pragma unroll
    for (int mi = 0; mi < 2; ++mi)
        #pragma unroll
        for (int ni = 0; ni < 4; ++ni) {
            hh[mi][ni] = (f32x4){0.f, 0.f, 0.f, 0.f};
            xx[mi][ni] = (f32x4){0.f, 0.f, 0.f, 0.f};
        }

    #pragma unroll
    for (int ks = 0; ks < 2; ++ks) {
        int kbyte = ks * 64 + ((lane >> 4) << 4);
        half8 qh[2], ql[2], kh[4], kl[4];
        #pragma unroll
        for (int mi = 0; mi < 2; ++mi) {
            int r = wv * 32 + mi * 16 + (lane & 15);
            int ad = (r * 128 + kbyte) ^ ((r & 7) << 4);
            qh[mi] = *(const half8*)(lds + SQH_OFF + ad);
            ql[mi] = *(const half8*)(lds + SQL_OFF + ad);
        }
        #pragma unroll
        for (int ni = 0; ni < 4; ++ni) {
            int r = ni * 16 + (lane & 15);
            int ad = (r * 128 + kbyte) ^ ((r & 7) << 4);
            kh[ni] = *(const half8*)(lds + SKH_OFF + ad);
            kl[ni] = *(const half8*)(lds + SKL_OFF + ad);
        }
        #pragma unroll
        for (int mi = 0; mi < 2; ++mi)
            #pragma unroll
            for (int ni = 0; ni < 4; ++ni) {
                hh[mi][ni] = __builtin_amdgcn_mfma_f32_16x16x32_f16(qh[mi], kh[ni], hh[mi][ni], 0, 0, 0);
                xx[mi][ni] = __builtin_amdgcn_mfma_f32_16x16x32_f16(qh[mi], kl[ni], xx[mi][ni], 0, 0, 0);
                xx[mi][ni] = __builtin_amdgcn_mfma_f32_16x16x32_f16(ql[mi], kh[ni], xx[mi][ni], 0, 0, 0);
            }
    }

    #pragma unroll
    for (int mi = 0; mi < 2; ++mi)
        #pragma unroll
        for (int ni = 0; ni < 4; ++ni) {
            int col = j0 + ni * 16 + (lane & 15);
            int rowb = i0 + wv * 32 + mi * 16 + ((lane >> 4) << 2);
            #pragma unroll
            for (int j = 0; j < 4; ++j) {
                float s = SCALE * (hh[mi][ni][j] + xx[mi][ni][j] * INV2048);
                Sc[(size_t)(rowb + j) * SEQ + col] = s;
            }
        }
}

// ---------------- K3: exact top-K via linear-bin histogram (Newton fallback) + softmax + P.V ----------------
// lw layout: entry n lives at slot (n&15)*34 + (n>>4) -> each 16-lane PV group reads
// its entries contiguously as uint4 (2 entries per ds_read_b128); stride 34 breaks bank aliasing.
__global__ __launch_bounds__(256) void topk_attn_kernel(const float* __restrict__ V,
                                                        const float* __restrict__ Sc,
                                                        float* __restrict__ Out, int b) {
    __shared__ unsigned int hist[4][256];   // 4 KB wave-private linear-bin histograms
    __shared__ __align__(16) uint2 lw[16 * 34];   // 4.25 KB padded entry store
    __shared__ float pvred[1024];           // 4 KB
    __shared__ unsigned int wredA[4];
    __shared__ unsigned int wredB[4];
    __shared__ unsigned int wsumS[4];
    __shared__ unsigned int wsumC[4];
    __shared__ float fred0[4];
    __shared__ float fred1[4];
    __shared__ unsigned int smax4[4];
    __shared__ unsigned int swin[3];
    __shared__ unsigned int cand[32];
    __shared__ unsigned int scand;

    const int t = threadIdx.x;
    const int lane = t & 63;
    const int wv = t >> 6;
    const unsigned long long ltmask = (1ull << lane) - 1ull;

    if (t == 0) { swin[0] = 0xFFFFFFFFu; scand = 0u; }
    {
        uint4 z = {0u, 0u, 0u, 0u};
        ((uint4*)hist)[t] = z;
    }

    // ---- load 16 scores/thread into register keys; fused sum/sumsq/max ----
    const float* row = Sc + (size_t)blockIdx.x * SEQ;
    unsigned int key[16];
    float fsum = 0.0f, fss = 0.0f;
    unsigned int mk = 0;
    #pragma unroll
    for (int u = 0; u < 4; ++u) {
        float4 v4 = *(const float4*)&row[u * 1024 + t * 4];
        float f[4] = {v4.x, v4.y, v4.z, v4.w};
        #pragma unroll
        for (int c = 0; c < 4; ++c) {
            unsigned int k = fkey(f[c]);
            key[u * 4 + c] = k;
            mk = max(mk, k);
            fsum += f[c];
            fss = fmaf(f[c], f[c], fss);
        }
    }
    #pragma unroll
    for (int off = 32; off >= 1; off >>= 1) {
        fsum += __shfl_xor(fsum, off);
        fss  += __shfl_xor(fss, off);
        mk = max(mk, (unsigned int)__shfl_xor(mk, off));
    }
    if (lane == 0) { fred0[wv] = fsum; fred1[wv] = fss; smax4[wv] = mk; }
    __syncthreads();   // B1
    const float mu = (fred0[0] + fred0[1] + fred0[2] + fred0[3]) * (1.0f / 4096.0f);
    const float ms = (fred1[0] + fred1[1] + fred1[2] + fred1[3]) * (1.0f / 4096.0f);
    const float sg = sqrtf(fmaxf(ms - mu * mu, 1e-12f));
    const float invsg = 1.0f / sg;
    const float m = ikey(max(max(smax4[0], smax4[1]), max(smax4[2], smax4[3])));

    // ---- linear-bin histogram over bracket [blo, bhi) ----
    const float blo = mu + 0.85f * sg;
    const float bhi = mu + 1.75f * sg;
    const float wdt = bhi - blo;
    const bool degen = !(wdt > 0.0f);
    const float sc256 = degen ? 0.0f : 256.0f / wdt;
    const unsigned int kblo = fkey(blo);

    if (!degen) {
        #pragma unroll
        for (int su = 0; su < 16; ++su) {
            unsigned int k = key[su];
            if (k >= kblo) {
                int bin = (int)((ikey(k) - blo) * sc256);
                bin = bin > 255 ? 255 : bin;
                atomicAdd(&hist[wv][bin], 1u);
            }
        }
    }
    __syncthreads();   // B2

    // ---- suffix scan (descending bins): thread t owns bin 255-t ----
    {
        int bb = 255 - t;
        unsigned int cb = hist[0][bb] + hist[1][bb] + hist[2][bb] + hist[3][bb];
        unsigned int incl = cb;
        #pragma unroll
        for (int off = 1; off < 64; off <<= 1) {
            unsigned int o = __shfl_up(incl, off);
            if (lane >= off) incl += o;
        }
        if (lane == 63) wsumS[wv] = incl;
        __syncthreads();   // B3
        unsigned int wb = 0;
        for (int w2 = 0; w2 < wv; ++w2) wb += wsumS[w2];
        unsigned int sumGE = wb + incl;
        unsigned int A = sumGE - cb;
        if (A < (unsigned)KSP && sumGE >= (unsigned)KSP) {
            swin[0] = (unsigned)bb; swin[1] = A; swin[2] = cb;
        }
    }
    __syncthreads();   // B4

    const unsigned int bwin = swin[0];
    const bool hist_ok = (bwin != 0xFFFFFFFFu) && !degen;
    if (hist_ok) {
        #pragma unroll
        for (int su = 0; su < 16; ++su) {
            unsigned int k = key[su];
            if (k >= kblo) {
                int bin = (int)((ikey(k) - blo) * sc256);
                bin = bin > 255 ? 255 : bin;
                if ((unsigned)bin == bwin) {
                    unsigned int id = atomicAdd(&scand, 1u);
                    if (id < 32u) cand[id] = k;
                }
            }
        }
    }
    __syncthreads();   // B5

    unsigned int thrk = 0;
    const unsigned int nc = scand;
    bool need_fb = (!hist_ok) || (nc > 32u);
    if (!need_fb) {
        unsigned int remain = (unsigned)KSP - swin[1];
        if (remain > nc) {
            need_fb = true;
        } else {
            for (unsigned int i = 0; i < nc; ++i) {
                unsigned int v = cand[i];
                unsigned int g = 0, e = 0;
                for (unsigned int j2 = 0; j2 < nc; ++j2) {
                    unsigned int u2 = cand[j2];
                    g += (u2 > v) ? 1u : 0u;
                    e += (u2 == v) ? 1u : 0u;
                }
                if (g < remain && remain <= g + e) thrk = v;
            }
        }
    }
    if (need_fb) {
        unsigned int lo = 0u, hi = 0xFFFFFFFFu;
        float T = mu + 1.2817f * sg;
        bool early = false;
        int par = 0;
        for (int iter = 0; iter < 40 && lo < hi; ++iter) {
            unsigned int P;
            if (iter < 6) {
                P = fkey(T);
                if (P < lo || P >= hi) P = lo + ((hi - lo) >> 1);
            } else {
                P = lo + ((hi - lo) >> 1);
            }
            unsigned int c = 0;
            #pragma unroll
            for (int su = 0; su < 16; ++su) c += (key[su] > P) ? 1u : 0u;
            #pragma unroll
            for (int off = 32; off >= 1; off >>= 1) c += __shfl_xor(c, off);
            unsigned int* buf = par ? wredB : wredA;
            if (lane == 0) buf[wv] = c;
            __syncthreads();
            c = buf[0] + buf[1] + buf[2] + buf[3];
            par ^= 1;
            if (c >= (unsigned)KSP) {
                if (c == (unsigned)KSP) { thrk = P + 1u; early = true; break; }
                lo = P + 1u;
            } else {
                hi = P;
            }
            float Tp = ikey(P);
            float z = (Tp - mu) * invsg;
            float dens = 1634.0f * __expf(-0.5f * z * z);
            float step = ((float)(int)(c - (unsigned)KSP)) / fmaxf(dens, 8.0f);
            step = fminf(fmaxf(step, -1.0f), 1.0f);
            T = Tp + step * sg;
        }
        if (!early) thrk = lo;
    }

    // ---- compaction of selected (key >= thrk) into padded slot layout ----
    unsigned long long msk[16];
    unsigned int wt = 0;
    #pragma unroll
    for (int su = 0; su < 16; ++su) {
        msk[su] = __ballot(key[su] >= thrk);
        wt += (unsigned int)__popcll(msk[su]);
    }
    if (lane == 0) wsumC[wv] = wt;
    __syncthreads();
    unsigned int wbase = 0;
    for (int w2 = 0; w2 < wv; ++w2) wbase += wsumC[w2];
    const unsigned int total = wsumC[0] + wsumC[1] + wsumC[2] + wsumC[3];
    const int cc = (int)(total < LISTCAP ? total : LISTCAP);

    unsigned int pos = wbase;
    #pragma unroll
    for (int su = 0; su < 16; ++su) {
        if (key[su] >= thrk) {
            unsigned int myoff = pos + (unsigned int)__popcll(msk[su] & ltmask);
            if (myoff < LISTCAP) {
                unsigned int j = (unsigned)((su >> 2) * 1024 + t * 4 + (su & 3));
                lw[(myoff & 15) * 34 + (myoff >> 4)] = make_uint2(j << 6, key[su]);
            }
        }
        pos += (unsigned int)__popcll(msk[su]);
    }
    __syncthreads();

    // ---- deferred exp over compacted list (2 entries/thread) + Z reduce ----
    float lsum = 0.0f;
    #pragma unroll
    for (int r = 0; r < 2; ++r) {
        int n = t + 256 * r;
        if (n < cc) {
            int s = (n & 15) * 34 + (n >> 4);
            uint2 e = lw[s];
            float w = __expf(ikey(e.y) - m);
            lw[s].y = __float_as_uint(w);
            lsum += w;
        }
    }
    #pragma unroll
    for (int off = 32; off >= 1; off >>= 1) lsum += __shfl_xor(lsum, off);
    if (lane == 0) fred0[wv] = lsum;
    __syncthreads();
    const float Zinv = 1.0f / (fred0[0] + fred0[1] + fred0[2] + fred0[3]);

    // ---- P.V : group gi reads its entries as uint4 (2 per LDS op), paired gathers ----
    const int q = lane & 15;
    const int g = lane >> 4;
    const int gi = wv * 4 + g;
    const float* vbase = V + (size_t)b * SEQ * HD + 4 * q;
    const uint4* base4 = (const uint4*)(lw + gi * 34);
    float a0 = 0.f, a1 = 0.f, a2 = 0.f, a3 = 0.f;
    #pragma unroll 2
    for (int s2 = 0; s2 < 16; ++s2) {
        int n0 = s2 * 32 + gi;
        if (n0 >= cc) break;
        uint4 e2 = base4[s2];
        bool v1ok = (n0 + 16) < cc;
        float w0 = __uint_as_float(e2.y);
        float w1 = v1ok ? __uint_as_float(e2.w) : 0.0f;
        unsigned int o1 = v1ok ? e2.z : 0u;
        float4 v0 = *(const float4*)(vbase + e2.x);
        float4 v1 = *(const float4*)(vbase + o1);
        a0 = fmaf(w0, v0.x, a0);
        a1 = fmaf(w0, v0.y, a1);
        a2 = fmaf(w0, v0.z, a2);
        a3 = fmaf(w0, v0.w, a3);
        a0 = fmaf(w1, v1.x, a0);
        a1 = fmaf(w1, v1.y, a1);
        a2 = fmaf(w1, v1.z, a2);
        a3 = fmaf(w1, v1.w, a3);
    }
    pvred[wv * 256 + g * 64 + 4 * q + 0] = a0;
    pvred[wv * 256 + g * 64 + 4 * q + 1] = a1;
    pvred[wv * 256 + g * 64 + 4 * q + 2] = a2;
    pvred[wv * 256 + g * 64 + 4 * q + 3] = a3;
    __syncthreads();
    if (t < 64) {
        float o = 0.f;
        #pragma unroll
        for (int w2 = 0; w2 < 4; ++w2)
            #pragma unroll
            for (int g2 = 0; g2 < 4; ++g2)
                o += pvred[w2 * 256 + g2 * 64 + t];
        Out[((size_t)b * SEQ + blockIdx.x) * HD + t] = o * Zinv;
    }
}

extern "C" void kernel_launch(void* const* d_in, const int* in_sizes, int n_in,
                              void* d_out, int out_size, void* d_ws, size_t ws_size,
                              hipStream_t stream) {
    (void)in_sizes; (void)n_in; (void)out_size; (void)ws_size;
    const float* X = (const float*)d_in[0];       // [4,4096,1024]
    const float* W = (const float*)d_in[1];       // [192,1024]
    float* Out = (float*)d_out;                   // [4,4096,64]

    char* ws = (char*)d_ws;
    const size_t V_BYTES  = (size_t)BATCH * SEQ * HD * 4;
    const size_t SC_BYTES = (size_t)SEQ * SEQ * 4;
    const size_t WH_BYTES = (size_t)EE * DMODEL * 2;
    const size_t QH_BYTES = (size_t)BATCH * SEQ * HD * 2;

    float*    Vv  = (float*)(ws);
    float*    sc  = (float*)(ws + V_BYTES);
    _Float16* Whi = (_Float16*)(ws + V_BYTES + SC_BYTES);
    _Float16* Wlo = (_Float16*)(ws + V_BYTES + SC_BYTES + WH_BYTES);
    _Float16* QH  = (_Float16*)(ws + V_BYTES + SC_BYTES + 2 * WH_BYTES);
    _Float16* QL  = (_Float16*)(ws + V_BYTES + SC_BYTES + 2 * WH_BYTES + QH_BYTES);
    _Float16* KH  = (_Float16*)(ws + V_BYTES + SC_BYTES + 2 * WH_BYTES + 2 * QH_BYTES);
    _Float16* KL  = (_Float16*)(ws + V_BYTES + SC_BYTES + 2 * WH_BYTES + 3 * QH_BYTES);

    wsplit_kernel<<<EE, 256, 0, stream>>>(W, Whi, Wlo);
    qkv_mfma_kernel<<<512, 256, 0, stream>>>(X, Whi, Wlo, QH, QL, KH, KL, Vv);
    for (int b = 0; b < BATCH; ++b) {
        scores_mfma_kernel<<<dim3(64, 32), 256, 0, stream>>>(
            QH + (size_t)b * SEQ * HD, QL + (size_t)b * SEQ * HD,
            KH + (size_t)b * SEQ * HD, KL + (size_t)b * SEQ * HD, sc);
        topk_attn_kernel<<<SEQ, 256, 0, stream>>>(Vv, sc, Out, b);
    }
}

// Round 16
// 272.043 us; speedup vs baseline: 1.0225x; 1.0225x over previous
//
#include <hip/hip_runtime.h>
#include <math.h>

#define BATCH 4
#define SEQ 4096
#define DMODEL 1024
#define HD 64
#define EE 192          // 3*HD
#define KSP 409         // max(1, int(4096*0.1))
#define SCALE 0.125f
#define LISTCAP 512
#define INV2048 (1.0f/2048.0f)

using half8 = __attribute__((ext_vector_type(8))) _Float16;
using half4 = __attribute__((ext_vector_type(4))) _Float16;
using f32x4 = __attribute__((ext_vector_type(4))) float;

__device__ __forceinline__ unsigned int fkey(float f) {
    unsigned int u = __float_as_uint(f);
    return (u & 0x80000000u) ? ~u : (u | 0x80000000u);
}
__device__ __forceinline__ float ikey(unsigned int k) {
    unsigned int u = (k & 0x80000000u) ? (k ^ 0x80000000u) : ~k;
    return __uint_as_float(u);
}

// ---------------- K0: split W into fp16 hi/lo (lo scaled by 2^11) ----------------
__global__ __launch_bounds__(256) void wsplit_kernel(const float* __restrict__ W,
                                                     _Float16* __restrict__ Whi,
                                                     _Float16* __restrict__ Wlo) {
    int i = blockIdx.x * 1024 + threadIdx.x * 4;
    float4 w = *(const float4*)&W[i];
    float f[4] = {w.x, w.y, w.z, w.w};
    half4 hv, lv;
    #pragma unroll
    for (int j = 0; j < 4; ++j) {
        _Float16 h = (_Float16)f[j];
        hv[j] = h;
        lv[j] = (_Float16)((f[j] - (float)h) * 2048.0f);
    }
    *(half4*)&Whi[i] = hv;
    *(half4*)&Wlo[i] = lv;
}

// ---------------- K1: QKV via fp16 split-3 MFMA (measured-best form) ----------------
#define AH_OFF 0
#define AL_OFF 4096
#define BH_OFF 8192
#define BL_OFF 14336

__global__ __launch_bounds__(256) void qkv_mfma_kernel(const float* __restrict__ X,
        const _Float16* __restrict__ Whi, const _Float16* __restrict__ Wlo,
        _Float16* __restrict__ QH, _Float16* __restrict__ QL,
        _Float16* __restrict__ KH, _Float16* __restrict__ KL,
        float* __restrict__ V) {
    __shared__ __align__(16) unsigned char lds[20480];
    const int t = threadIdx.x;
    const int lane = t & 63;
    const int wv = t >> 6;
    const int wr = wv >> 1, wc = wv & 1;
    const int L = blockIdx.x;
    const int pair = ((L >> 4) << 3) + (L & 7);
    const int ny = (L >> 3) & 1;
    const int m0 = pair * 64;
    const int n0 = ny * 96;

    const int ar = t >> 2;
    const int akc = (t & 3) * 8;
    const int aw_addr = ((ar * 64 + (t & 3) * 16) ^ ((ar & 7) << 4));
    const int br0 = t >> 2;
    const int bw0 = ((br0 * 64 + (t & 3) * 16) ^ ((br0 & 7) << 4));
    const int br1 = 64 + (t >> 2);
    const int bw1 = ((br1 * 64 + (t & 3) * 16) ^ ((br1 & 7) << 4));

    float4 xa, xb;
    uint4 pbh0, pbl0, pbh1, pbl1;

    #define LOADG(K0) { \
        const float* xp = X + (size_t)(m0 + ar) * DMODEL + (K0) + akc; \
        xa = *(const float4*)xp; xb = *(const float4*)(xp + 4); \
        size_t wo0 = (size_t)(n0 + br0) * DMODEL + (K0) + akc; \
        pbh0 = *(const uint4*)(Whi + wo0); pbl0 = *(const uint4*)(Wlo + wo0); \
        if (t < 128) { \
            size_t wo1 = (size_t)(n0 + br1) * DMODEL + (K0) + akc; \
            pbh1 = *(const uint4*)(Whi + wo1); pbl1 = *(const uint4*)(Wlo + wo1); \
        } }

    #define WRITE_LDS() { \
        float f[8] = {xa.x, xa.y, xa.z, xa.w, xb.x, xb.y, xb.z, xb.w}; \
        half8 hv, lv; \
        _Pragma("unroll") \
        for (int i2 = 0; i2 < 8; ++i2) { \
            _Float16 h = (_Float16)f[i2]; \
            hv[i2] = h; \
            lv[i2] = (_Float16)((f[i2] - (float)h) * 2048.0f); \
        } \
        *(half8*)(lds + AH_OFF + aw_addr) = hv; \
        *(half8*)(lds + AL_OFF + aw_addr) = lv; \
        *(uint4*)(lds + BH_OFF + bw0) = pbh0; \
        *(uint4*)(lds + BL_OFF + bw0) = pbl0; \
        if (t < 128) { \
            *(uint4*)(lds + BH_OFF + bw1) = pbh1; \
            *(uint4*)(lds + BL_OFF + bw1) = pbl1; \
        } }

    f32x4 hh[2][3], xx[2][3];
    #pragma unroll
    for (int mi = 0; mi < 2; ++mi)
        #pragma unroll
        for (int ni = 0; ni < 3; ++ni) {
            hh[mi][ni] = (f32x4){0.f, 0.f, 0.f, 0.f};
            xx[mi][ni] = (f32x4){0.f, 0.f, 0.f, 0.f};
        }

    LOADG(0);
    WRITE_LDS();
    __syncthreads();

    const int kb = (lane >> 4) << 4;

    for (int it = 0; it < 32; ++it) {
        if (it < 31) LOADG((it + 1) * 32);

        half8 ah[2], al[2], bh[3], bl[3];
        #pragma unroll
        for (int mi = 0; mi < 2; ++mi) {
            int ra = wr * 32 + mi * 16 + (lane & 15);
            int ad = ((ra * 64 + kb) ^ ((ra & 7) << 4));
            ah[mi] = *(const half8*)(lds + AH_OFF + ad);
            al[mi] = *(const half8*)(lds + AL_OFF + ad);
        }
        #pragma unroll
        for (int ni = 0; ni < 3; ++ni) {
            int rb = wc * 48 + ni * 16 + (lane & 15);
            int bd = ((rb * 64 + kb) ^ ((rb & 7) << 4));
            bh[ni] = *(const half8*)(lds + BH_OFF + bd);
            bl[ni] = *(const half8*)(lds + BL_OFF + bd);
        }
        #pragma unroll
        for (int mi = 0; mi < 2; ++mi)
            #pragma unroll
            for (int ni = 0; ni < 3; ++ni) {
                hh[mi][ni] = __builtin_amdgcn_mfma_f32_16x16x32_f16(ah[mi], bh[ni], hh[mi][ni], 0, 0, 0);
                xx[mi][ni] = __builtin_amdgcn_mfma_f32_16x16x32_f16(ah[mi], bl[ni], xx[mi][ni], 0, 0, 0);
                xx[mi][ni] = __builtin_amdgcn_mfma_f32_16x16x32_f16(al[mi], bh[ni], xx[mi][ni], 0, 0, 0);
            }
        __syncthreads();
        if (it < 31) { WRITE_LDS(); __syncthreads(); }
    }

    #pragma unroll
    for (int mi = 0; mi < 2; ++mi)
        #pragma unroll
        for (int ni = 0; ni < 3; ++ni) {
            int col = n0 + wc * 48 + ni * 16 + (lane & 15);
            int rowb = m0 + wr * 32 + mi * 16 + ((lane >> 4) << 2);
            #pragma unroll
            for (int j = 0; j < 4; ++j) {
                float val = hh[mi][ni][j] + xx[mi][ni][j] * INV2048;
                int row = rowb + j;
                if (col < 64) {
                    _Float16 h = (_Float16)val;
                    QH[(size_t)row * HD + col] = h;
                    QL[(size_t)row * HD + col] = (_Float16)((val - (float)h) * 2048.0f);
                } else if (col < 128) {
                    _Float16 h = (_Float16)val;
                    KH[(size_t)row * HD + (col - 64)] = h;
                    KL[(size_t)row * HD + (col - 64)] = (_Float16)((val - (float)h) * 2048.0f);
                } else {
                    V[(size_t)row * HD + (col - 128)] = val;
                }
            }
        }
}

// ---------------- K2: scores via fp16 split-3 MFMA ----------------
#define SQH_OFF 0
#define SQL_OFF 16384
#define SKH_OFF 32768
#define SKL_OFF 40960

__global__ __launch_bounds__(256) void scores_mfma_kernel(
        const _Float16* __restrict__ QH, const _Float16* __restrict__ QL,
        const _Float16* __restrict__ KH, const _Float16* __restrict__ KL,
        float* __restrict__ Sc) {
    __shared__ __align__(16) unsigned char lds[49152];
    const int t = threadIdx.x;
    const int lane = t & 63;
    const int wv = t >> 6;
    const int i0 = blockIdx.y * 128;
    const int j0 = blockIdx.x * 64;

    #pragma unroll
    for (int u = 0; u < 4; ++u) {
        int ch = t + 256 * u;
        int r = ch >> 3;
        int kbyte = (ch & 7) * 16;
        int ad = (r * 128 + kbyte) ^ ((r & 7) << 4);
        *(uint4*)(lds + SQH_OFF + ad) = *(const uint4*)((const char*)QH + (size_t)(i0 + r) * 128 + kbyte);
        *(uint4*)(lds + SQL_OFF + ad) = *(const uint4*)((const char*)QL + (size_t)(i0 + r) * 128 + kbyte);
    }
    #pragma unroll
    for (int u = 0; u < 2; ++u) {
        int ch = t + 256 * u;
        int r = ch >> 3;
        int kbyte = (ch & 7) * 16;
        int ad = (r * 128 + kbyte) ^ ((r & 7) << 4);
        *(uint4*)(lds + SKH_OFF + ad) = *(const uint4*)((const char*)KH + (size_t)(j0 + r) * 128 + kbyte);
        *(uint4*)(lds + SKL_OFF + ad) = *(const uint4*)((const char*)KL + (size_t)(j0 + r) * 128 + kbyte);
    }
    __syncthreads();

    f32x4 hh[2][4], xx[2][4];
    #pragma unroll
    for (int mi = 0; mi < 2; ++mi)
        #pragma unroll
        for (int ni = 0; ni < 4; ++ni) {
            hh[mi][ni] = (f32x4){0.f, 0.f, 0.f, 0.f};
            xx[mi][ni] = (f32x4){0.f, 0.f, 0.f, 0.f};
        }

    #pragma unroll
    for (int ks = 0; ks < 2; ++ks) {
        int kbyte = ks * 64 + ((lane >> 4) << 4);
        half8 qh[2], ql[2], kh[4], kl[4];
        #pragma unroll
        for (int mi = 0; mi < 2; ++mi) {
            int r = wv * 32 + mi * 16 + (lane & 15);
            int ad = (r * 128 + kbyte) ^ ((r & 7) << 4);
            qh[mi] = *(const half8*)(lds + SQH_OFF + ad);
            ql[mi] = *(const half8*)(lds + SQL_OFF + ad);
        }
        #pragma unroll
        for (int ni = 0; ni < 4; ++ni) {
            int r = ni * 16 + (lane & 15);
            int ad = (r * 128 + kbyte) ^ ((r & 7) << 4);
            kh[ni] = *(const half8*)(lds + SKH_OFF + ad);
            kl[ni] = *(const half8*)(lds + SKL_OFF + ad);
        }
        #pragma unroll
        for (int mi = 0; mi < 2; ++mi)
            #pragma unroll
            for (int ni = 0; ni < 4; ++ni) {
                hh[mi][ni] = __builtin_amdgcn_mfma_f32_16x16x32_f16(qh[mi], kh[ni], hh[mi][ni], 0, 0, 0);
                xx[mi][ni] = __builtin_amdgcn_mfma_f32_16x16x32_f16(qh[mi], kl[ni], xx[mi][ni], 0, 0, 0);
                xx[mi][ni] = __builtin_amdgcn_mfma_f32_16x16x32_f16(ql[mi], kh[ni], xx[mi][ni], 0, 0, 0);
            }
    }

    #pragma unroll
    for (int mi = 0; mi < 2; ++mi)
        #pragma unroll
        for (int ni = 0; ni < 4; ++ni) {
            int col = j0 + ni * 16 + (lane & 15);
            int rowb = i0 + wv * 32 + mi * 16 + ((lane >> 4) << 2);
            #pragma unroll
            for (int j = 0; j < 4; ++j) {
                float s = SCALE * (hh[mi][ni][j] + xx[mi][ni][j] * INV2048);
                Sc[(size_t)(rowb + j) * SEQ + col] = s;
            }
        }
}

// ---------------- K3: exact top-K via linear-bin histogram (Newton fallback) + softmax + P.V ----------------
__global__ __launch_bounds__(256) void topk_attn_kernel(const float* __restrict__ V,
                                                        const float* __restrict__ Sc,
                                                        float* __restrict__ Out, int b) {
    __shared__ unsigned int hist[4][256];   // 4 KB wave-private linear-bin histograms
    __shared__ uint2 lw[LISTCAP];           // 4 KB
    __shared__ float pvred[1024];           // 4 KB
    __shared__ unsigned int wredA[4];
    __shared__ unsigned int wredB[4];
    __shared__ unsigned int wsumS[4];
    __shared__ unsigned int wsumC[4];
    __shared__ float fred0[4];
    __shared__ float fred1[4];
    __shared__ unsigned int smax4[4];
    __shared__ unsigned int swin[3];        // winning bin, A(above count), c(bin count)
    __shared__ unsigned int cand[32];
    __shared__ unsigned int scand;

    const int t = threadIdx.x;
    const int lane = t & 63;
    const int wv = t >> 6;
    const unsigned long long ltmask = (1ull << lane) - 1ull;

    if (t == 0) { swin[0] = 0xFFFFFFFFu; scand = 0u; }
    {
        uint4 z = {0u, 0u, 0u, 0u};
        ((uint4*)hist)[t] = z;
    }

    // ---- load 16 scores/thread into register keys; fused sum/sumsq/max ----
    const float* row = Sc + (size_t)blockIdx.x * SEQ;
    unsigned int key[16];
    float fsum = 0.0f, fss = 0.0f;
    unsigned int mk = 0;
    #pragma unroll
    for (int u = 0; u < 4; ++u) {
        float4 v4 = *(const float4*)&row[u * 1024 + t * 4];
        float f[4] = {v4.x, v4.y, v4.z, v4.w};
        #pragma unroll
        for (int c = 0; c < 4; ++c) {
            unsigned int k = fkey(f[c]);
            key[u * 4 + c] = k;
            mk = max(mk, k);
            fsum += f[c];
            fss = fmaf(f[c], f[c], fss);
        }
    }
    #pragma unroll
    for (int off = 32; off >= 1; off >>= 1) {
        fsum += __shfl_xor(fsum, off);
        fss  += __shfl_xor(fss, off);
        mk = max(mk, (unsigned int)__shfl_xor(mk, off));
    }
    if (lane == 0) { fred0[wv] = fsum; fred1[wv] = fss; smax4[wv] = mk; }
    __syncthreads();   // B1: stats + hist-zero + inits visible
    const float mu = (fred0[0] + fred0[1] + fred0[2] + fred0[3]) * (1.0f / 4096.0f);
    const float ms = (fred1[0] + fred1[1] + fred1[2] + fred1[3]) * (1.0f / 4096.0f);
    const float sg = sqrtf(fmaxf(ms - mu * mu, 1e-12f));
    const float invsg = 1.0f / sg;
    const float m = ikey(max(max(smax4[0], smax4[1]), max(smax4[2], smax4[3])));

    // ---- linear-bin histogram over bracket [blo, bhi); keys >= bhi clamp to bin 255 ----
    const float blo = mu + 0.85f * sg;
    const float bhi = mu + 1.75f * sg;
    const float wdt = bhi - blo;
    const bool degen = !(wdt > 0.0f);
    const float sc256 = degen ? 0.0f : 256.0f / wdt;
    const unsigned int kblo = fkey(blo);

    if (!degen) {
        #pragma unroll
        for (int su = 0; su < 16; ++su) {
            unsigned int k = key[su];
            if (k >= kblo) {
                int bin = (int)((ikey(k) - blo) * sc256);
                bin = bin > 255 ? 255 : bin;
                atomicAdd(&hist[wv][bin], 1u);
            }
        }
    }
    __syncthreads();   // B2: histogram complete

    // ---- suffix scan (descending bins): thread t owns bin 255-t ----
    {
        int bb = 255 - t;
        unsigned int cb = hist[0][bb] + hist[1][bb] + hist[2][bb] + hist[3][bb];
        unsigned int incl = cb;
        #pragma unroll
        for (int off = 1; off < 64; off <<= 1) {
            unsigned int o = __shfl_up(incl, off);
            if (lane >= off) incl += o;
        }
        if (lane == 63) wsumS[wv] = incl;
        __syncthreads();   // B3
        unsigned int wb = 0;
        for (int w2 = 0; w2 < wv; ++w2) wb += wsumS[w2];
        unsigned int sumGE = wb + incl;     // # keys in bins >= bb
        unsigned int A = sumGE - cb;        // # keys in bins > bb
        if (A < (unsigned)KSP && sumGE >= (unsigned)KSP) {
            swin[0] = (unsigned)bb; swin[1] = A; swin[2] = cb;
        }
    }
    __syncthreads();   // B4: winner visible

    const unsigned int bwin = swin[0];
    const bool hist_ok = (bwin != 0xFFFFFFFFu) && !degen;
    if (hist_ok) {
        #pragma unroll
        for (int su = 0; su < 16; ++su) {
            unsigned int k = key[su];
            if (k >= kblo) {
                int bin = (int)((ikey(k) - blo) * sc256);
                bin = bin > 255 ? 255 : bin;
                if ((unsigned)bin == bwin) {
                    unsigned int id = atomicAdd(&scand, 1u);
                    if (id < 32u) cand[id] = k;
                }
            }
        }
    }
    __syncthreads();   // B5: candidates visible

    unsigned int thrk = 0;
    const unsigned int nc = scand;
    bool need_fb = (!hist_ok) || (nc > 32u);
    if (!need_fb) {
        unsigned int remain = (unsigned)KSP - swin[1];
        if (remain > nc) {
            need_fb = true;
        } else {
            // exact rank among <=32 candidates; uniform work, broadcast LDS reads
            for (unsigned int i = 0; i < nc; ++i) {
                unsigned int v = cand[i];
                unsigned int g = 0, e = 0;
                for (unsigned int j2 = 0; j2 < nc; ++j2) {
                    unsigned int u2 = cand[j2];
                    g += (u2 > v) ? 1u : 0u;
                    e += (u2 == v) ? 1u : 0u;
                }
                if (g < remain && remain <= g + e) thrk = v;
            }
        }
    }
    if (need_fb) {
        // ---- Newton-guided exact count search (rare; guaranteed-correct) ----
        unsigned int lo = 0u, hi = 0xFFFFFFFFu;
        float T = mu + 1.2817f * sg;
        bool early = false;
        int par = 0;
        for (int iter = 0; iter < 40 && lo < hi; ++iter) {
            unsigned int P;
            if (iter < 6) {
                P = fkey(T);
                if (P < lo || P >= hi) P = lo + ((hi - lo) >> 1);
            } else {
                P = lo + ((hi - lo) >> 1);
            }
            unsigned int c = 0;
            #pragma unroll
            for (int su = 0; su < 16; ++su) c += (key[su] > P) ? 1u : 0u;
            #pragma unroll
            for (int off = 32; off >= 1; off >>= 1) c += __shfl_xor(c, off);
            unsigned int* buf = par ? wredB : wredA;
            if (lane == 0) buf[wv] = c;
            __syncthreads();
            c = buf[0] + buf[1] + buf[2] + buf[3];
            par ^= 1;
            if (c >= (unsigned)KSP) {
                if (c == (unsigned)KSP) { thrk = P + 1u; early = true; break; }
                lo = P + 1u;
            } else {
                hi = P;
            }
            float Tp = ikey(P);
            float z = (Tp - mu) * invsg;
            float dens = 1634.0f * __expf(-0.5f * z * z);
            float step = ((float)(int)(c - (unsigned)KSP)) / fmaxf(dens, 8.0f);
            step = fminf(fmaxf(step, -1.0f), 1.0f);
            T = Tp + step * sg;
        }
        if (!early) thrk = lo;
    }

    // ---- compaction of selected (key >= thrk): ballot once, store (j*64, key) ----
    unsigned long long msk[16];
    unsigned int wt = 0;
    #pragma unroll
    for (int su = 0; su < 16; ++su) {
        msk[su] = __ballot(key[su] >= thrk);
        wt += (unsigned int)__popcll(msk[su]);
    }
    if (lane == 0) wsumC[wv] = wt;
    __syncthreads();
    unsigned int wbase = 0;
    for (int w2 = 0; w2 < wv; ++w2) wbase += wsumC[w2];
    const unsigned int total = wsumC[0] + wsumC[1] + wsumC[2] + wsumC[3];
    const int cc = (int)(total < LISTCAP ? total : LISTCAP);

    unsigned int pos = wbase;
    #pragma unroll
    for (int su = 0; su < 16; ++su) {
        if (key[su] >= thrk) {
            unsigned int myoff = pos + (unsigned int)__popcll(msk[su] & ltmask);
            if (myoff < LISTCAP) {
                unsigned int j = (unsigned)((su >> 2) * 1024 + t * 4 + (su & 3));
                lw[myoff] = make_uint2(j << 6, key[su]);
            }
        }
        pos += (unsigned int)__popcll(msk[su]);
    }
    __syncthreads();

    // ---- deferred exp over compacted list (2 entries/thread) + Z reduce ----
    float lsum = 0.0f;
    #pragma unroll
    for (int r = 0; r < 2; ++r) {
        int n = t + 256 * r;
        if (n < cc) {
            uint2 e = lw[n];
            float w = __expf(ikey(e.y) - m);
            lw[n].y = __float_as_uint(w);
            lsum += w;
        }
    }
    #pragma unroll
    for (int off = 32; off >= 1; off >>= 1) lsum += __shfl_xor(lsum, off);
    if (lane == 0) fred0[wv] = lsum;
    __syncthreads();
    const float Zinv = 1.0f / (fred0[0] + fred0[1] + fred0[2] + fred0[3]);

    // ---- P.V : 16 entries per block-iter; lane = 16*g + q, q holds dims 4q..4q+3 ----
    const int q = lane & 15;
    const int g = lane >> 4;
    const float* vbase = V + (size_t)b * SEQ * HD + 4 * q;
    float a0 = 0.f, a1 = 0.f, a2 = 0.f, a3 = 0.f;
    #pragma unroll 2
    for (int n = wv * 4 + g; n < cc; n += 16) {
        uint2 e = lw[n];
        float w = __uint_as_float(e.y);
        float4 v4 = *(const float4*)(vbase + e.x);
        a0 = fmaf(w, v4.x, a0);
        a1 = fmaf(w, v4.y, a1);
        a2 = fmaf(w, v4.z, a2);
        a3 = fmaf(w, v4.w, a3);
    }
    pvred[wv * 256 + g * 64 + 4 * q + 0] = a0;
    pvred[wv * 256 + g * 64 + 4 * q + 1] = a1;
    pvred[wv * 256 + g * 64 + 4 * q + 2] = a2;
    pvred[wv * 256 + g * 64 + 4 * q + 3] = a3;
    __syncthreads();
    if (t < 64) {
        float o = 0.f;
        #pragma unroll
        for (int w2 = 0; w2 < 4; ++w2)
            #pragma unroll
            for (int g2 = 0; g2 < 4; ++g2)
                o += pvred[w2 * 256 + g2 * 64 + t];
        Out[((size_t)b * SEQ + blockIdx.x) * HD + t] = o * Zinv;
    }
}

extern "C" void kernel_launch(void* const* d_in, const int* in_sizes, int n_in,
                              void* d_out, int out_size, void* d_ws, size_t ws_size,
                              hipStream_t stream) {
    (void)in_sizes; (void)n_in; (void)out_size; (void)ws_size;
    const float* X = (const float*)d_in[0];       // [4,4096,1024]
    const float* W = (const float*)d_in[1];       // [192,1024]
    float* Out = (float*)d_out;                   // [4,4096,64]

    char* ws = (char*)d_ws;
    const size_t V_BYTES  = (size_t)BATCH * SEQ * HD * 4;
    const size_t SC_BYTES = (size_t)SEQ * SEQ * 4;
    const size_t WH_BYTES = (size_t)EE * DMODEL * 2;
    const size_t QH_BYTES = (size_t)BATCH * SEQ * HD * 2;

    float*    Vv  = (float*)(ws);
    float*    sc  = (float*)(ws + V_BYTES);
    _Float16* Whi = (_Float16*)(ws + V_BYTES + SC_BYTES);
    _Float16* Wlo = (_Float16*)(ws + V_BYTES + SC_BYTES + WH_BYTES);
    _Float16* QH  = (_Float16*)(ws + V_BYTES + SC_BYTES + 2 * WH_BYTES);
    _Float16* QL  = (_Float16*)(ws + V_BYTES + SC_BYTES + 2 * WH_BYTES + QH_BYTES);
    _Float16* KH  = (_Float16*)(ws + V_BYTES + SC_BYTES + 2 * WH_BYTES + 2 * QH_BYTES);
    _Float16* KL  = (_Float16*)(ws + V_BYTES + SC_BYTES + 2 * WH_BYTES + 3 * QH_BYTES);

    wsplit_kernel<<<EE, 256, 0, stream>>>(W, Whi, Wlo);
    qkv_mfma_kernel<<<512, 256, 0, stream>>>(X, Whi, Wlo, QH, QL, KH, KL, Vv);
    for (int b = 0; b < BATCH; ++b) {
        scores_mfma_kernel<<<dim3(64, 32), 256, 0, stream>>>(
            QH + (size_t)b * SEQ * HD, QL + (size_t)b * SEQ * HD,
            KH + (size_t)b * SEQ * HD, KL + (size_t)b * SEQ * HD, sc);
        topk_attn_kernel<<<SEQ, 256, 0, stream>>>(Vv, sc, Out, b);
    }
}